// Round 5
// baseline (197.970 us; speedup 1.0000x reference)
//
#include <hip/hip_runtime.h>
#include <hip/hip_bf16.h>

// Problem constants
constexpr int NQ   = 4096;   // spatial tokens (H*W)
constexpr int NKV  = 4112;   // spatial + 16 memory tokens
constexpr int NP   = 4160;   // padded rows (65 * 64), pad is zeroed
constexpr int CDIM = 128;
constexpr int NSL  = 4;      // split-K slices (1024 keys each; slice 3 + tail)
constexpr float QSC = 0.17677669529663687f * 1.4426950408889634f; // DH^-0.5 * log2(e)

typedef __attribute__((ext_vector_type(8)))  short bf16x8;
typedef __attribute__((ext_vector_type(4)))  short bf16x4;
typedef __attribute__((ext_vector_type(4)))  float f32x4;
typedef __attribute__((ext_vector_type(16))) float f32x16;

static __device__ __forceinline__ unsigned short bfbits(float f) {
  __hip_bfloat16 h = __float2bfloat16(f);
  return *reinterpret_cast<unsigned short*>(&h);
}
static __device__ __forceinline__ unsigned pk2(float a, float b) {
  return (unsigned)bfbits(a) | ((unsigned)bfbits(b) << 16);
}

// ---------------- Kernel 1: QKV projection (+ w_out cast) ----------------
// grid (65, 4 batches), block 256.  Writes:
//   Qt[bh][n][d] (bf16, pre-scaled by QSC), Kt[bh][n][d], Vt[bh][d][n]
__global__ __launch_bounds__(256) void k1_qkv(
    const float* __restrict__ x, const float* __restrict__ memry,
    const float* __restrict__ wqkv, const float* __restrict__ wout,
    __hip_bfloat16* __restrict__ Qt, __hip_bfloat16* __restrict__ Kt,
    __hip_bfloat16* __restrict__ Vt, __hip_bfloat16* __restrict__ Wb) {
  __shared__ __align__(16) __hip_bfloat16 xt[64][136];  // [n-local][c], +8 pad
  const int b  = blockIdx.y;
  const int nb = blockIdx.x * 64;
  const int t  = threadIdx.x;
  const int wv = t >> 6, ln = t & 63;

  if (blockIdx.x == 0 && b == 0) {
    for (int i = t; i < CDIM * CDIM; i += 256) Wb[i] = __float2bfloat16(wout[i]);
  }

  { // stage x_ext tile (transposed, bf16)
    const int n = nb + ln;
    #pragma unroll
    for (int i = 0; i < 16; ++i) {
      const int c = wv * 32 + 2 * i;
      float v0 = 0.f, v1 = 0.f;
      if (n < NQ)        { v0 = x[((size_t)b * CDIM + c) * NQ + n];
                           v1 = x[((size_t)b * CDIM + c + 1) * NQ + n]; }
      else if (n < NKV)  { v0 = memry[c * 16 + (n - NQ)];
                           v1 = memry[(c + 1) * 16 + (n - NQ)]; }
      *reinterpret_cast<unsigned*>(&xt[ln][c]) =
          (unsigned)bfbits(v0) | ((unsigned)bfbits(v1) << 16);
    }
  }
  __syncthreads();

  const int li = ln & 15, g = ln >> 4;
  bf16x8 xa[4][4];
  #pragma unroll
  for (int nt = 0; nt < 4; ++nt)
    #pragma unroll
    for (int k = 0; k < 4; ++k)
      xa[nt][k] = *reinterpret_cast<const bf16x8*>(&xt[nt * 16 + li][k * 32 + 8 * g]);

  #pragma unroll
  for (int oi = 0; oi < 6; ++oi) {
    const int ot = wv * 6 + oi;                 // 24 o-tiles of 16: 0-7 Q, 8-15 K, 16-23 V
    bf16x8 wf[4];
    #pragma unroll
    for (int k = 0; k < 4; ++k) {
      const float* wp = &wqkv[(size_t)(ot * 16 + li) * CDIM + k * 32 + 8 * g];
      const float4 f0 = *reinterpret_cast<const float4*>(wp);
      const float4 f1 = *reinterpret_cast<const float4*>(wp + 4);
      bf16x8 wc;
      wc[0] = (short)bfbits(f0.x); wc[1] = (short)bfbits(f0.y);
      wc[2] = (short)bfbits(f0.z); wc[3] = (short)bfbits(f0.w);
      wc[4] = (short)bfbits(f1.x); wc[5] = (short)bfbits(f1.y);
      wc[6] = (short)bfbits(f1.z); wc[7] = (short)bfbits(f1.w);
      wf[k] = wc;
    }
    #pragma unroll
    for (int nt = 0; nt < 4; ++nt) {
      f32x4 a; a[0] = a[1] = a[2] = a[3] = 0.f;
      if (ot < 16) {
        // D[row=n][col=o]  (A = x-tile, B = W^T)
        #pragma unroll
        for (int k = 0; k < 4; ++k)
          a = __builtin_amdgcn_mfma_f32_16x16x32_bf16(xa[nt][k], wf[k], a, 0, 0, 0);
        const int o = ot * 16 + li;
        const int h = (o >> 5) & 3, d = o & 31;
        if (ot < 8) {
          #pragma unroll
          for (int r = 0; r < 4; ++r) {
            const int n = nb + nt * 16 + 4 * g + r;
            Qt[((size_t)(b * 4 + h) * NP + n) * 32 + d] = __float2bfloat16(a[r] * QSC);
          }
        } else {
          #pragma unroll
          for (int r = 0; r < 4; ++r) {
            const int n = nb + nt * 16 + 4 * g + r;
            Kt[((size_t)(b * 4 + h) * NP + n) * 32 + d] = __float2bfloat16(a[r]);
          }
        }
      } else {
        // D[row=o][col=n]  (A = W, B = x-tile)
        #pragma unroll
        for (int k = 0; k < 4; ++k)
          a = __builtin_amdgcn_mfma_f32_16x16x32_bf16(wf[k], xa[nt][k], a, 0, 0, 0);
        #pragma unroll
        for (int r = 0; r < 4; ++r) {
          const int o = ot * 16 + 4 * g + r;
          const int h = (o >> 5) & 3, d = o & 31;
          const int n = nb + nt * 16 + li;
          Vt[((size_t)(b * 4 + h) * 32 + d) * NP + n] = __float2bfloat16(a[r]);
        }
      }
    }
  }
}

// ---------------- Kernel 2: attention partials, split-K ----------------
// Parallelism was capped at 2 waves/SIMD (q-parallel only). No-max softmax
// is associative, so split the key range into NSL slices; each block emits
// f32 partials (P = sum p*V^T, L = sum p). Combined in k2b.
// grid (32 q-blocks, 16 bh, NSL slices), block 256 = 4 waves, 32 q per wave.

#if __has_builtin(__builtin_amdgcn_mfma_f32_32x32x8bf16_1k)
#define HAS_PV8 1
#else
#define HAS_PV8 0
#endif

#if HAS_PV8
// 32 keys: S^T = K·Q^T via 32x32x16; P quads feed 32x32x8 PV directly.
__device__ __forceinline__ void attn32(
    const bf16x8& kf0, const bf16x8& kf1,
    const bf16x4& vf0, const bf16x4& vf1, const bf16x4& vf2, const bf16x4& vf3,
    const bf16x8& qf0, const bf16x8& qf1, const f32x16& z,
    f32x16& accA, f32x16& accB,
    float& l0, float& l1, float& l2, float& l3) {
  f32x16 s = __builtin_amdgcn_mfma_f32_32x32x16_bf16(kf0, qf0, z, 0, 0, 0);
  s = __builtin_amdgcn_mfma_f32_32x32x16_bf16(kf1, qf1, s, 0, 0, 0);
  float p[16];
  #pragma unroll
  for (int r = 0; r < 16; ++r) p[r] = __builtin_amdgcn_exp2f(s[r]);
  l0 += (p[0] + p[1]) + (p[2] + p[3]);
  l1 += (p[4] + p[5]) + (p[6] + p[7]);
  l2 += (p[8] + p[9]) + (p[10] + p[11]);
  l3 += (p[12] + p[13]) + (p[14] + p[15]);
  union UU { unsigned u[2]; bf16x4 v; };
  UU a0, a1, a2, a3;  // quad r -> keys {0,8,16,24} + 4*hi + 0..3
  a0.u[0] = pk2(p[0], p[1]);   a0.u[1] = pk2(p[2], p[3]);
  a1.u[0] = pk2(p[4], p[5]);   a1.u[1] = pk2(p[6], p[7]);
  a2.u[0] = pk2(p[8], p[9]);   a2.u[1] = pk2(p[10], p[11]);
  a3.u[0] = pk2(p[12], p[13]); a3.u[1] = pk2(p[14], p[15]);
  accA = __builtin_amdgcn_mfma_f32_32x32x8bf16_1k(a0.v, vf0, accA, 0, 0, 0);
  accA = __builtin_amdgcn_mfma_f32_32x32x8bf16_1k(a1.v, vf1, accA, 0, 0, 0);
  accB = __builtin_amdgcn_mfma_f32_32x32x8bf16_1k(a2.v, vf2, accB, 0, 0, 0);
  accB = __builtin_amdgcn_mfma_f32_32x32x8bf16_1k(a3.v, vf3, accB, 0, 0, 0);
}
#else
// Fallback: PV via 32x32x16, one xor32 swap per 16-key half; V as bf16x8.
__device__ __forceinline__ void attn32(
    const bf16x8& kf0, const bf16x8& kf1,
    const bf16x8& vf80, const bf16x8& vf81, int hi,
    const bf16x8& qf0, const bf16x8& qf1, const f32x16& z,
    f32x16& accA, f32x16& accB,
    float& l0, float& l1, float& l2, float& l3) {
  f32x16 s = __builtin_amdgcn_mfma_f32_32x32x16_bf16(kf0, qf0, z, 0, 0, 0);
  s = __builtin_amdgcn_mfma_f32_32x32x16_bf16(kf1, qf1, s, 0, 0, 0);
  float p[16];
  #pragma unroll
  for (int r = 0; r < 16; ++r) p[r] = __builtin_amdgcn_exp2f(s[r]);
  l0 += (p[0] + p[1]) + (p[2] + p[3]);
  l1 += (p[4] + p[5]) + (p[6] + p[7]);
  l2 += (p[8] + p[9]) + (p[10] + p[11]);
  l3 += (p[12] + p[13]) + (p[14] + p[15]);
  unsigned a0u0 = pk2(p[0], p[1]),   a0u1 = pk2(p[2], p[3]);
  unsigned a1u0 = pk2(p[4], p[5]),   a1u1 = pk2(p[6], p[7]);
  unsigned a2u0 = pk2(p[8], p[9]),   a2u1 = pk2(p[10], p[11]);
  unsigned a3u0 = pk2(p[12], p[13]), a3u1 = pk2(p[14], p[15]);
  union U8 { unsigned u[4]; bf16x8 v; };
  {
    const unsigned s0 = __shfl_xor(hi ? a0u0 : a1u0, 32, 64);
    const unsigned s1 = __shfl_xor(hi ? a0u1 : a1u1, 32, 64);
    U8 f;
    f.u[0] = hi ? s0 : a0u0; f.u[1] = hi ? s1 : a0u1;
    f.u[2] = hi ? a1u0 : s0; f.u[3] = hi ? a1u1 : s1;
    accA = __builtin_amdgcn_mfma_f32_32x32x16_bf16(f.v, vf80, accA, 0, 0, 0);
  }
  {
    const unsigned s0 = __shfl_xor(hi ? a2u0 : a3u0, 32, 64);
    const unsigned s1 = __shfl_xor(hi ? a2u1 : a3u1, 32, 64);
    U8 f;
    f.u[0] = hi ? s0 : a2u0; f.u[1] = hi ? s1 : a2u1;
    f.u[2] = hi ? a3u0 : s0; f.u[3] = hi ? a3u1 : s1;
    accB = __builtin_amdgcn_mfma_f32_32x32x16_bf16(f.v, vf81, accB, 0, 0, 0);
  }
}
#endif

__global__ __launch_bounds__(256, 4) void k2_attn(
    const __hip_bfloat16* __restrict__ Qt, const __hip_bfloat16* __restrict__ Kt,
    const __hip_bfloat16* __restrict__ Vt, float* __restrict__ Pb,
    float* __restrict__ Lb) {
  const int bh = blockIdx.y;
  const int sl = blockIdx.z;
  const int wv = threadIdx.x >> 6, lane = threadIdx.x & 63;
  const int lq = lane & 31, hi = lane >> 5;
  const int qb = blockIdx.x * 128 + wv * 32;

  const bf16x8 qf0 = *reinterpret_cast<const bf16x8*>(
      Qt + ((size_t)bh * NP + qb + lq) * 32 + 8 * hi);
  const bf16x8 qf1 = *reinterpret_cast<const bf16x8*>(
      Qt + ((size_t)bh * NP + qb + lq) * 32 + 16 + 8 * hi);
  const __hip_bfloat16* Vrow = Vt + ((size_t)bh * 32 + lq) * NP;
  const __hip_bfloat16* Kp   = Kt + (size_t)bh * NP * 32 + (size_t)lq * 32 + 8 * hi;

  f32x16 acc0, acc1, z;
  #pragma unroll
  for (int i = 0; i < 16; ++i) { acc0[i] = 0.f; acc1[i] = 0.f; z[i] = 0.f; }
  float l0 = 0.f, l1 = 0.f, l2 = 0.f, l3 = 0.f;

  const int kb0 = sl * 1024;
  for (int it = 0; it < 16; ++it) {
    const int kb = kb0 + it * 64;
    const bf16x8 ck0 = *reinterpret_cast<const bf16x8*>(Kp + (size_t)kb * 32);
    const bf16x8 ck1 = *reinterpret_cast<const bf16x8*>(Kp + (size_t)kb * 32 + 16);
    const bf16x8 ck2 = *reinterpret_cast<const bf16x8*>(Kp + (size_t)(kb + 32) * 32);
    const bf16x8 ck3 = *reinterpret_cast<const bf16x8*>(Kp + (size_t)(kb + 32) * 32 + 16);
#if HAS_PV8
    const bf16x4 cv0 = *reinterpret_cast<const bf16x4*>(Vrow + kb + 4 * hi);
    const bf16x4 cv1 = *reinterpret_cast<const bf16x4*>(Vrow + kb + 8 + 4 * hi);
    const bf16x4 cv2 = *reinterpret_cast<const bf16x4*>(Vrow + kb + 16 + 4 * hi);
    const bf16x4 cv3 = *reinterpret_cast<const bf16x4*>(Vrow + kb + 24 + 4 * hi);
    const bf16x4 cv4 = *reinterpret_cast<const bf16x4*>(Vrow + kb + 32 + 4 * hi);
    const bf16x4 cv5 = *reinterpret_cast<const bf16x4*>(Vrow + kb + 40 + 4 * hi);
    const bf16x4 cv6 = *reinterpret_cast<const bf16x4*>(Vrow + kb + 48 + 4 * hi);
    const bf16x4 cv7 = *reinterpret_cast<const bf16x4*>(Vrow + kb + 56 + 4 * hi);
    attn32(ck0, ck1, cv0, cv1, cv2, cv3, qf0, qf1, z, acc0, acc1, l0, l1, l2, l3);
    attn32(ck2, ck3, cv4, cv5, cv6, cv7, qf0, qf1, z, acc0, acc1, l0, l1, l2, l3);
#else
    const bf16x8 cv80 = *reinterpret_cast<const bf16x8*>(Vrow + kb + 8 * hi);
    const bf16x8 cv81 = *reinterpret_cast<const bf16x8*>(Vrow + kb + 16 + 8 * hi);
    const bf16x8 cv82 = *reinterpret_cast<const bf16x8*>(Vrow + kb + 32 + 8 * hi);
    const bf16x8 cv83 = *reinterpret_cast<const bf16x8*>(Vrow + kb + 48 + 8 * hi);
    attn32(ck0, ck1, cv80, cv81, hi, qf0, qf1, z, acc0, acc1, l0, l1, l2, l3);
    attn32(ck2, ck3, cv82, cv83, hi, qf0, qf1, z, acc0, acc1, l0, l1, l2, l3);
#endif
  }

  if (sl == NSL - 1) {
    // tail: 16 real keys (4096..4111) = quads 0,1 of a 32-key tile at 4096
    const int kb = 4096;
    const bf16x8 kf0 = *reinterpret_cast<const bf16x8*>(Kp + (size_t)kb * 32);
    const bf16x8 kf1 = *reinterpret_cast<const bf16x8*>(Kp + (size_t)kb * 32 + 16);
    f32x16 s = __builtin_amdgcn_mfma_f32_32x32x16_bf16(kf0, qf0, z, 0, 0, 0);
    s = __builtin_amdgcn_mfma_f32_32x32x16_bf16(kf1, qf1, s, 0, 0, 0);
    float p[8];
    #pragma unroll
    for (int r = 0; r < 8; ++r) p[r] = __builtin_amdgcn_exp2f(s[r]);
    l0 += (p[0] + p[1]) + (p[2] + p[3]);
    l1 += (p[4] + p[5]) + (p[6] + p[7]);
#if HAS_PV8
    union UU { unsigned u[2]; bf16x4 v; };
    UU a0, a1;
    a0.u[0] = pk2(p[0], p[1]); a0.u[1] = pk2(p[2], p[3]);
    a1.u[0] = pk2(p[4], p[5]); a1.u[1] = pk2(p[6], p[7]);
    const bf16x4 vf0 = *reinterpret_cast<const bf16x4*>(Vrow + kb + 4 * hi);
    const bf16x4 vf1 = *reinterpret_cast<const bf16x4*>(Vrow + kb + 8 + 4 * hi);
    acc0 = __builtin_amdgcn_mfma_f32_32x32x8bf16_1k(a0.v, vf0, acc0, 0, 0, 0);
    acc0 = __builtin_amdgcn_mfma_f32_32x32x8bf16_1k(a1.v, vf1, acc0, 0, 0, 0);
#else
    unsigned a0u0 = pk2(p[0], p[1]), a0u1 = pk2(p[2], p[3]);
    unsigned a1u0 = pk2(p[4], p[5]), a1u1 = pk2(p[6], p[7]);
    union U8 { unsigned u[4]; bf16x8 v; };
    const unsigned s0 = __shfl_xor(hi ? a0u0 : a1u0, 32, 64);
    const unsigned s1 = __shfl_xor(hi ? a0u1 : a1u1, 32, 64);
    U8 f;
    f.u[0] = hi ? s0 : a0u0; f.u[1] = hi ? s1 : a0u1;
    f.u[2] = hi ? a1u0 : s0; f.u[3] = hi ? a1u1 : s1;
    const bf16x8 vf = *reinterpret_cast<const bf16x8*>(Vrow + kb + 8 * hi);
    acc0 = __builtin_amdgcn_mfma_f32_32x32x16_bf16(f.v, vf, acc0, 0, 0, 0);
#endif
  }

  // write partials: P[sl][bh][q][d] (d = lq), L[sl][bh][q]
  float* Pp = Pb + (((size_t)sl * 16 + bh) * NQ + qb) * 32;
  #pragma unroll
  for (int r = 0; r < 16; ++r) {
    const int q = (r & 3) + 8 * (r >> 2) + 4 * hi;
    Pp[(size_t)q * 32 + lq] = acc0[r] + acc1[r];
  }
  float lsum = (l0 + l1) + (l2 + l3);       // partial for q = lq (this hi)
  lsum += __shfl_xor(lsum, 32, 64);
  if (hi == 0)
    Lb[((size_t)sl * 16 + bh) * NQ + qb + lq] = lsum;
}

// ---------------- Kernel 2b: combine split-K partials ----------------
// att[bh][q][d] = (sum_s P[s][bh][q][d]) / (sum_s L[s][bh][q])   (bf16)
// grid (256), block 256: one thread per (bh, q).
__global__ __launch_bounds__(256) void k2b_combine(
    const float* __restrict__ Pb, const float* __restrict__ Lb,
    __hip_bfloat16* __restrict__ att) {
  const int idx = blockIdx.x * 256 + threadIdx.x;   // 65536
  const int bh = idx >> 12;
  const int q  = idx & 4095;
  constexpr size_t PS = (size_t)16 * NQ * 32;       // per-slice P elements
  constexpr size_t LS = (size_t)16 * NQ;            // per-slice L elements
  const float* p = Pb + ((size_t)bh * NQ + q) * 32;

  float l = 0.f;
  #pragma unroll
  for (int s = 0; s < NSL; ++s) l += Lb[s * LS + (size_t)bh * NQ + q];
  const float inv = 1.f / l;

  float o[32];
  #pragma unroll
  for (int j = 0; j < 8; ++j) {
    const float4 f = *reinterpret_cast<const float4*>(p + 4 * j);
    o[4*j] = f.x; o[4*j+1] = f.y; o[4*j+2] = f.z; o[4*j+3] = f.w;
  }
  #pragma unroll
  for (int s = 1; s < NSL; ++s)
    #pragma unroll
    for (int j = 0; j < 8; ++j) {
      const float4 f = *reinterpret_cast<const float4*>(p + s * PS + 4 * j);
      o[4*j] += f.x; o[4*j+1] += f.y; o[4*j+2] += f.z; o[4*j+3] += f.w;
    }

  unsigned wb[16];
  #pragma unroll
  for (int j = 0; j < 16; ++j) wb[j] = pk2(o[2*j] * inv, o[2*j+1] * inv);
  __hip_bfloat16* dst = att + ((size_t)bh * NQ + q) * 32;
  *reinterpret_cast<uint4*>(dst)      = make_uint4(wb[0],  wb[1],  wb[2],  wb[3]);
  *reinterpret_cast<uint4*>(dst + 8)  = make_uint4(wb[4],  wb[5],  wb[6],  wb[7]);
  *reinterpret_cast<uint4*>(dst + 16) = make_uint4(wb[8],  wb[9],  wb[10], wb[11]);
  *reinterpret_cast<uint4*>(dst + 24) = make_uint4(wb[12], wb[13], wb[14], wb[15]);
}

// ---------------- Kernel 3: output projection ----------------
// grid (64 n-tiles, 4 batches), block 256.  out[b][o][n] = W·att + b
// att layout is (bh, q, d): head k, d-range 8g..8g+7 for row n.
__global__ __launch_bounds__(256) void k3_proj(
    const __hip_bfloat16* __restrict__ att, const __hip_bfloat16* __restrict__ Wb,
    const float* __restrict__ bout, float* __restrict__ out) {
  const int b = blockIdx.y, nb = blockIdx.x * 64;
  const int wv = threadIdx.x >> 6, lane = threadIdx.x & 63;
  const int li = lane & 15, g = lane >> 4;

  bf16x8 wf[2][4];
  float bo[2][4];
  #pragma unroll
  for (int tt = 0; tt < 2; ++tt) {
    const int ot = 2 * wv + tt;
    #pragma unroll
    for (int k = 0; k < 4; ++k)
      wf[tt][k] = *reinterpret_cast<const bf16x8*>(
          &Wb[(size_t)(ot * 16 + li) * CDIM + k * 32 + 8 * g]);
    #pragma unroll
    for (int r = 0; r < 4; ++r) bo[tt][r] = bout[ot * 16 + 4 * g + r];
  }
  #pragma unroll
  for (int nt = 0; nt < 4; ++nt) {
    bf16x8 bfr[4];
    #pragma unroll
    for (int k = 0; k < 4; ++k)
      bfr[k] = *reinterpret_cast<const bf16x8*>(
          &att[(((size_t)(b * 4 + k)) * NQ + nb + nt * 16 + li) * 32 + 8 * g]);
    #pragma unroll
    for (int tt = 0; tt < 2; ++tt) {
      f32x4 a; a[0] = a[1] = a[2] = a[3] = 0.f;
      #pragma unroll
      for (int k = 0; k < 4; ++k)
        a = __builtin_amdgcn_mfma_f32_16x16x32_bf16(wf[tt][k], bfr[k], a, 0, 0, 0);
      const int ot = 2 * wv + tt;
      #pragma unroll
      for (int r = 0; r < 4; ++r)
        out[((size_t)b * CDIM + ot * 16 + 4 * g + r) * NQ + nb + nt * 16 + li] =
            a[r] + bo[tt][r];
    }
  }
}

extern "C" void kernel_launch(void* const* d_in, const int* in_sizes, int n_in,
                              void* d_out, int out_size, void* d_ws, size_t ws_size,
                              hipStream_t stream) {
  const float* x    = (const float*)d_in[0];
  const float* memp = (const float*)d_in[1];
  const float* wqkv = (const float*)d_in[2];
  const float* wout = (const float*)d_in[3];
  const float* bout = (const float*)d_in[4];
  float* out = (float*)d_out;

  char* ws = (char*)d_ws;
  const size_t SZ  = (size_t)16 * NP * 32 * 2;              // Qt/Kt/Vt each
  const size_t PSZ = (size_t)NSL * 16 * NQ * 32 * 4;        // 33.5 MB
  const size_t LSZ = (size_t)NSL * 16 * NQ * 4;             // 1 MB
  __hip_bfloat16* Qt  = (__hip_bfloat16*)(ws);
  __hip_bfloat16* Kt  = (__hip_bfloat16*)(ws + SZ);
  __hip_bfloat16* Vt  = (__hip_bfloat16*)(ws + 2 * SZ);
  float*          Pbf = (float*)(ws + 3 * SZ);
  float*          Lbf = (float*)(ws + 3 * SZ + PSZ);
  __hip_bfloat16* Wb  = (__hip_bfloat16*)(ws + 3 * SZ + PSZ + LSZ);
  __hip_bfloat16* att = Qt;   // overlay: Qt is dead once k2 finishes

  hipLaunchKernelGGL(k1_qkv, dim3(65, 4), dim3(256), 0, stream,
                     x, memp, wqkv, wout, Qt, Kt, Vt, Wb);
  hipLaunchKernelGGL(k2_attn, dim3(32, 16, NSL), dim3(256), 0, stream,
                     Qt, Kt, Vt, Pbf, Lbf);
  hipLaunchKernelGGL(k2b_combine, dim3(256), dim3(256), 0, stream, Pbf, Lbf, att);
  hipLaunchKernelGGL(k3_proj, dim3(64, 4), dim3(256), 0, stream, att, Wb, bout, out);
}

// Round 6
// 92.885 us; speedup vs baseline: 2.1313x; 2.1313x over previous
//
#include <hip/hip_runtime.h>
#include <hip/hip_bf16.h>

// Problem constants
constexpr int NQ   = 4096;   // spatial tokens (H*W)
constexpr int NKV  = 4112;   // spatial + 16 memory tokens
constexpr int NP   = 4160;   // padded rows (65 * 64), pad is zeroed
constexpr int CDIM = 128;
constexpr float QSC = 0.17677669529663687f * 1.4426950408889634f; // DH^-0.5 * log2(e)

typedef __attribute__((ext_vector_type(8)))  short bf16x8;
typedef __attribute__((ext_vector_type(4)))  short bf16x4;
typedef __attribute__((ext_vector_type(4)))  float f32x4;
typedef __attribute__((ext_vector_type(16))) float f32x16;

static __device__ __forceinline__ unsigned short bfbits(float f) {
  __hip_bfloat16 h = __float2bfloat16(f);
  return *reinterpret_cast<unsigned short*>(&h);
}
static __device__ __forceinline__ unsigned pk2(float a, float b) {
  return (unsigned)bfbits(a) | ((unsigned)bfbits(b) << 16);
}

// ---------------- Kernel 1: QKV projection (+ w_out cast) ----------------
// grid (65, 4 batches), block 256.  Writes:
//   Qt[bh][n][d] (bf16, pre-scaled by QSC), Kt[bh][n][d], Vt[bh][d][n]
__global__ __launch_bounds__(256) void k1_qkv(
    const float* __restrict__ x, const float* __restrict__ memry,
    const float* __restrict__ wqkv, const float* __restrict__ wout,
    __hip_bfloat16* __restrict__ Qt, __hip_bfloat16* __restrict__ Kt,
    __hip_bfloat16* __restrict__ Vt, __hip_bfloat16* __restrict__ Wb) {
  __shared__ __align__(16) __hip_bfloat16 xt[64][136];  // [n-local][c], +8 pad
  const int b  = blockIdx.y;
  const int nb = blockIdx.x * 64;
  const int t  = threadIdx.x;
  const int wv = t >> 6, ln = t & 63;

  if (blockIdx.x == 0 && b == 0) {
    for (int i = t; i < CDIM * CDIM; i += 256) Wb[i] = __float2bfloat16(wout[i]);
  }

  { // stage x_ext tile (transposed, bf16)
    const int n = nb + ln;
    #pragma unroll
    for (int i = 0; i < 16; ++i) {
      const int c = wv * 32 + 2 * i;
      float v0 = 0.f, v1 = 0.f;
      if (n < NQ)        { v0 = x[((size_t)b * CDIM + c) * NQ + n];
                           v1 = x[((size_t)b * CDIM + c + 1) * NQ + n]; }
      else if (n < NKV)  { v0 = memry[c * 16 + (n - NQ)];
                           v1 = memry[(c + 1) * 16 + (n - NQ)]; }
      *reinterpret_cast<unsigned*>(&xt[ln][c]) =
          (unsigned)bfbits(v0) | ((unsigned)bfbits(v1) << 16);
    }
  }
  __syncthreads();

  const int li = ln & 15, g = ln >> 4;
  bf16x8 xa[4][4];
  #pragma unroll
  for (int nt = 0; nt < 4; ++nt)
    #pragma unroll
    for (int k = 0; k < 4; ++k)
      xa[nt][k] = *reinterpret_cast<const bf16x8*>(&xt[nt * 16 + li][k * 32 + 8 * g]);

  #pragma unroll
  for (int oi = 0; oi < 6; ++oi) {
    const int ot = wv * 6 + oi;                 // 24 o-tiles of 16: 0-7 Q, 8-15 K, 16-23 V
    bf16x8 wf[4];
    #pragma unroll
    for (int k = 0; k < 4; ++k) {
      const float* wp = &wqkv[(size_t)(ot * 16 + li) * CDIM + k * 32 + 8 * g];
      const float4 f0 = *reinterpret_cast<const float4*>(wp);
      const float4 f1 = *reinterpret_cast<const float4*>(wp + 4);
      bf16x8 wc;
      wc[0] = (short)bfbits(f0.x); wc[1] = (short)bfbits(f0.y);
      wc[2] = (short)bfbits(f0.z); wc[3] = (short)bfbits(f0.w);
      wc[4] = (short)bfbits(f1.x); wc[5] = (short)bfbits(f1.y);
      wc[6] = (short)bfbits(f1.z); wc[7] = (short)bfbits(f1.w);
      wf[k] = wc;
    }
    #pragma unroll
    for (int nt = 0; nt < 4; ++nt) {
      f32x4 a; a[0] = a[1] = a[2] = a[3] = 0.f;
      if (ot < 16) {
        // D[row=n][col=o]  (A = x-tile, B = W^T)
        #pragma unroll
        for (int k = 0; k < 4; ++k)
          a = __builtin_amdgcn_mfma_f32_16x16x32_bf16(xa[nt][k], wf[k], a, 0, 0, 0);
        const int o = ot * 16 + li;
        const int h = (o >> 5) & 3, d = o & 31;
        if (ot < 8) {
          #pragma unroll
          for (int r = 0; r < 4; ++r) {
            const int n = nb + nt * 16 + 4 * g + r;
            Qt[((size_t)(b * 4 + h) * NP + n) * 32 + d] = __float2bfloat16(a[r] * QSC);
          }
        } else {
          #pragma unroll
          for (int r = 0; r < 4; ++r) {
            const int n = nb + nt * 16 + 4 * g + r;
            Kt[((size_t)(b * 4 + h) * NP + n) * 32 + d] = __float2bfloat16(a[r]);
          }
        }
      } else {
        // D[row=o][col=n]  (A = W, B = x-tile)
        #pragma unroll
        for (int k = 0; k < 4; ++k)
          a = __builtin_amdgcn_mfma_f32_16x16x32_bf16(wf[k], xa[nt][k], a, 0, 0, 0);
        #pragma unroll
        for (int r = 0; r < 4; ++r) {
          const int o = ot * 16 + 4 * g + r;
          const int h = (o >> 5) & 3, d = o & 31;
          const int n = nb + nt * 16 + li;
          Vt[((size_t)(b * 4 + h) * 32 + d) * NP + n] = __float2bfloat16(a[r]);
        }
      }
    }
  }
}

// ---------------- Kernel 2: attention, LDS-staged, XCD-pinned ----------------
// All prior variants pinned at ~155us moving 1.09 GB through L3 (per-XCD K/V
// working set 17MB > 4MB L2 -> every read hits Infinity Cache at ~7 TB/s).
// Fix: (a) pin each bh to one XCD (2 bh/XCD -> 1.6MB L2-resident set),
// (b) LDS-stage K/V per block (4 waves share each byte), (c) no split-K.
// grid 512 flat blocks, block 256 = 4 waves, 32 q per wave (128 q per block).

#if __has_builtin(__builtin_amdgcn_mfma_f32_32x32x8bf16_1k)
#define HAS_PV8 1
#else
#define HAS_PV8 0
#endif

__global__ __launch_bounds__(256, 2) void k2_attn(
    const __hip_bfloat16* __restrict__ Qt, const __hip_bfloat16* __restrict__ Kt,
    const __hip_bfloat16* __restrict__ Vt, __hip_bfloat16* __restrict__ att) {
  // LDS: staging (K 4KB + V 4KB) overlaid later by the epilogue transpose
  __shared__ __align__(16) unsigned char smem[16896];
  __hip_bfloat16* kbuf = (__hip_bfloat16*)smem;            // [4KB] frag-ordered
  __hip_bfloat16* vbuf = (__hip_bfloat16*)(smem + 4096);   // [4KB] frag-ordered
  float (*olds)[32][33] = (float(*)[32][33])smem;          // epilogue overlay

  // XCD-pinned decomposition (assumes xcd = blockIdx % 8; perf-only heuristic)
  const int wg  = blockIdx.x;          // 0..511
  const int xcd = wg & 7;
  const int i   = wg >> 3;             // 0..63
  const int bh  = 2 * xcd + (i & 1);   // 2 bh per XCD
  const int wv  = threadIdx.x >> 6, lane = threadIdx.x & 63;
  const int lq  = lane & 31, hi = lane >> 5;
  const int qb  = (i >> 1) * 128 + wv * 32;   // q-block 0..31 -> 128q each

  const bf16x8 qf0 = *reinterpret_cast<const bf16x8*>(
      Qt + ((size_t)bh * NP + qb + lq) * 32 + 8 * hi);
  const bf16x8 qf1 = *reinterpret_cast<const bf16x8*>(
      Qt + ((size_t)bh * NP + qb + lq) * 32 + 16 + 8 * hi);

  // Staging sources: wave wv owns chunk c=wv (1KB each) of K-tile and V-tile.
  // K chunk c: LDS[c*512 + l*8 elems] = K[kb + (c>>1)*32 + (l&31)][(c&1)*16 + 8*(l>>5) ..+8]
  // V chunk c: LDS[c*512 + l*8 elems] = V^T-row[d=(l&31)][kb + c*16 + 8*(l>>5) ..+8]
  const __hip_bfloat16* Ksrc = Kt + ((size_t)bh * NP + (wv >> 1) * 32 + lq) * 32
                                  + (wv & 1) * 16 + 8 * hi;
  const __hip_bfloat16* Vsrc = Vt + ((size_t)bh * 32 + lq) * NP + wv * 16 + 8 * hi;
  __hip_bfloat16* kdst = kbuf + wv * 512 + lane * 8;
  __hip_bfloat16* vdst = vbuf + wv * 512 + lane * 8;

  f32x16 acc0, acc1, z;
  #pragma unroll
  for (int q = 0; q < 16; ++q) { acc0[q] = 0.f; acc1[q] = 0.f; z[q] = 0.f; }
  float l0 = 0.f, l1 = 0.f, l2 = 0.f, l3 = 0.f;

  // prologue: tile 0 into regs
  bf16x8 kreg = *reinterpret_cast<const bf16x8*>(Ksrc);
  bf16x8 vreg = *reinterpret_cast<const bf16x8*>(Vsrc);

  for (int t = 0; t < 64; ++t) {
    *reinterpret_cast<bf16x8*>(kdst) = kreg;   // ds_write_b128
    *reinterpret_cast<bf16x8*>(vdst) = vreg;
    __syncthreads();
    if (t < 63) {  // prefetch next tile; latency hides under compute below
      kreg = *reinterpret_cast<const bf16x8*>(Ksrc + (size_t)(t + 1) * 2048);
      vreg = *reinterpret_cast<const bf16x8*>(Vsrc + (t + 1) * 64);
    }
    #pragma unroll
    for (int st = 0; st < 2; ++st) {           // two 32-key subtiles
      const bf16x8 kf0 = *reinterpret_cast<const bf16x8*>(kbuf + st * 1024 + lane * 8);
      const bf16x8 kf1 = *reinterpret_cast<const bf16x8*>(kbuf + st * 1024 + 512 + lane * 8);
      f32x16 s = __builtin_amdgcn_mfma_f32_32x32x16_bf16(kf0, qf0, z, 0, 0, 0);
      s = __builtin_amdgcn_mfma_f32_32x32x16_bf16(kf1, qf1, s, 0, 0, 0);
      float p[16];
      #pragma unroll
      for (int r = 0; r < 16; ++r) p[r] = __builtin_amdgcn_exp2f(s[r]);
      l0 += (p[0] + p[1]) + (p[2] + p[3]);
      l1 += (p[4] + p[5]) + (p[6] + p[7]);
      l2 += (p[8] + p[9]) + (p[10] + p[11]);
      l3 += (p[12] + p[13]) + (p[14] + p[15]);
#if HAS_PV8
      union UU { unsigned u[2]; bf16x4 v; };
      UU a0, a1, a2, a3;  // quad r -> keys {0,8,16,24} + 4*hi + 0..3
      a0.u[0] = pk2(p[0], p[1]);   a0.u[1] = pk2(p[2], p[3]);
      a1.u[0] = pk2(p[4], p[5]);   a1.u[1] = pk2(p[6], p[7]);
      a2.u[0] = pk2(p[8], p[9]);   a2.u[1] = pk2(p[10], p[11]);
      a3.u[0] = pk2(p[12], p[13]); a3.u[1] = pk2(p[14], p[15]);
      const __hip_bfloat16* vb = vbuf + st * 1024 + lq * 8 + hi * 4;
      const bf16x4 vf0 = *reinterpret_cast<const bf16x4*>(vb);        // keys +4hi
      const bf16x4 vf1 = *reinterpret_cast<const bf16x4*>(vb + 256);  // keys +8+4hi
      const bf16x4 vf2 = *reinterpret_cast<const bf16x4*>(vb + 512);  // keys +16+4hi
      const bf16x4 vf3 = *reinterpret_cast<const bf16x4*>(vb + 768);  // keys +24+4hi
      acc0 = __builtin_amdgcn_mfma_f32_32x32x8bf16_1k(a0.v, vf0, acc0, 0, 0, 0);
      acc0 = __builtin_amdgcn_mfma_f32_32x32x8bf16_1k(a1.v, vf1, acc0, 0, 0, 0);
      acc1 = __builtin_amdgcn_mfma_f32_32x32x8bf16_1k(a2.v, vf2, acc1, 0, 0, 0);
      acc1 = __builtin_amdgcn_mfma_f32_32x32x8bf16_1k(a3.v, vf3, acc1, 0, 0, 0);
#else
      unsigned a0u0 = pk2(p[0], p[1]),   a0u1 = pk2(p[2], p[3]);
      unsigned a1u0 = pk2(p[4], p[5]),   a1u1 = pk2(p[6], p[7]);
      unsigned a2u0 = pk2(p[8], p[9]),   a2u1 = pk2(p[10], p[11]);
      unsigned a3u0 = pk2(p[12], p[13]), a3u1 = pk2(p[14], p[15]);
      union U8 { unsigned u[4]; bf16x8 v; };
      const bf16x8 vh0 = *reinterpret_cast<const bf16x8*>(vbuf + (2 * st) * 512 + lane * 8);
      const bf16x8 vh1 = *reinterpret_cast<const bf16x8*>(vbuf + (2 * st + 1) * 512 + lane * 8);
      {
        const unsigned s0 = __shfl_xor(hi ? a0u0 : a1u0, 32, 64);
        const unsigned s1 = __shfl_xor(hi ? a0u1 : a1u1, 32, 64);
        U8 f;
        f.u[0] = hi ? s0 : a0u0; f.u[1] = hi ? s1 : a0u1;
        f.u[2] = hi ? a1u0 : s0; f.u[3] = hi ? a1u1 : s1;
        acc0 = __builtin_amdgcn_mfma_f32_32x32x16_bf16(f.v, vh0, acc0, 0, 0, 0);
      }
      {
        const unsigned s0 = __shfl_xor(hi ? a2u0 : a3u0, 32, 64);
        const unsigned s1 = __shfl_xor(hi ? a2u1 : a3u1, 32, 64);
        U8 f;
        f.u[0] = hi ? s0 : a2u0; f.u[1] = hi ? s1 : a2u1;
        f.u[2] = hi ? a3u0 : s0; f.u[3] = hi ? a3u1 : s1;
        acc1 = __builtin_amdgcn_mfma_f32_32x32x16_bf16(f.v, vh1, acc1, 0, 0, 0);
      }
#endif
    }
    __syncthreads();
  }

  { // tail: 16 real keys (4096..4111), direct from global (L2-hot, tiny)
    const __hip_bfloat16* Kp   = Kt + (size_t)bh * NP * 32 + (size_t)lq * 32 + 8 * hi;
    const __hip_bfloat16* Vrow = Vt + ((size_t)bh * 32 + lq) * NP;
    const int kb = 4096;
    const bf16x8 kf0 = *reinterpret_cast<const bf16x8*>(Kp + (size_t)kb * 32);
    const bf16x8 kf1 = *reinterpret_cast<const bf16x8*>(Kp + (size_t)kb * 32 + 16);
    f32x16 s = __builtin_amdgcn_mfma_f32_32x32x16_bf16(kf0, qf0, z, 0, 0, 0);
    s = __builtin_amdgcn_mfma_f32_32x32x16_bf16(kf1, qf1, s, 0, 0, 0);
    float p[8];
    #pragma unroll
    for (int r = 0; r < 8; ++r) p[r] = __builtin_amdgcn_exp2f(s[r]);
    l0 += (p[0] + p[1]) + (p[2] + p[3]);
    l1 += (p[4] + p[5]) + (p[6] + p[7]);
#if HAS_PV8
    union UU { unsigned u[2]; bf16x4 v; };
    UU a0, a1;
    a0.u[0] = pk2(p[0], p[1]); a0.u[1] = pk2(p[2], p[3]);
    a1.u[0] = pk2(p[4], p[5]); a1.u[1] = pk2(p[6], p[7]);
    const bf16x4 vf0 = *reinterpret_cast<const bf16x4*>(Vrow + kb + 4 * hi);
    const bf16x4 vf1 = *reinterpret_cast<const bf16x4*>(Vrow + kb + 8 + 4 * hi);
    acc0 = __builtin_amdgcn_mfma_f32_32x32x8bf16_1k(a0.v, vf0, acc0, 0, 0, 0);
    acc0 = __builtin_amdgcn_mfma_f32_32x32x8bf16_1k(a1.v, vf1, acc0, 0, 0, 0);
#else
    unsigned a0u0 = pk2(p[0], p[1]), a0u1 = pk2(p[2], p[3]);
    unsigned a1u0 = pk2(p[4], p[5]), a1u1 = pk2(p[6], p[7]);
    union U8 { unsigned u[4]; bf16x8 v; };
    const unsigned s0 = __shfl_xor(hi ? a0u0 : a1u0, 32, 64);
    const unsigned s1 = __shfl_xor(hi ? a0u1 : a1u1, 32, 64);
    U8 f;
    f.u[0] = hi ? s0 : a0u0; f.u[1] = hi ? s1 : a0u1;
    f.u[2] = hi ? a1u0 : s0; f.u[3] = hi ? a1u1 : s1;
    const bf16x8 vf = *reinterpret_cast<const bf16x8*>(Vrow + kb + 8 * hi);
    acc0 = __builtin_amdgcn_mfma_f32_32x32x16_bf16(f.v, vf, acc0, 0, 0, 0);
#endif
  }

  // epilogue: normalize by column sum, transpose through LDS (overlays staging)
  float lsum = (l0 + l1) + (l2 + l3);       // partial for q = lq (this hi)
  lsum += __shfl_xor(lsum, 32, 64);
  const float inv = 1.f / lsum;             // for q = lq

  __syncthreads();                          // staging area now dead everywhere
  #pragma unroll
  for (int r = 0; r < 16; ++r)
    olds[wv][(r & 3) + 8 * (r >> 2) + 4 * hi][lq] = acc0[r] + acc1[r]; // [q][d]
  __syncthreads();

  __hip_bfloat16* dst = att + ((size_t)bh * NQ + qb + lq) * 32 + hi * 16;
  unsigned wbuf[8];
  #pragma unroll
  for (int j = 0; j < 8; ++j)
    wbuf[j] = pk2(olds[wv][lq][hi * 16 + 2 * j] * inv,
                  olds[wv][lq][hi * 16 + 2 * j + 1] * inv);
  *reinterpret_cast<uint4*>(dst)     = make_uint4(wbuf[0], wbuf[1], wbuf[2], wbuf[3]);
  *reinterpret_cast<uint4*>(dst + 8) = make_uint4(wbuf[4], wbuf[5], wbuf[6], wbuf[7]);
}

// ---------------- Kernel 3: output projection ----------------
// grid (64 n-tiles, 4 batches), block 256.  out[b][o][n] = W·att + b
// att layout is (bh, q, d): head k, d-range 8g..8g+7 for row n.
__global__ __launch_bounds__(256) void k3_proj(
    const __hip_bfloat16* __restrict__ att, const __hip_bfloat16* __restrict__ Wb,
    const float* __restrict__ bout, float* __restrict__ out) {
  const int b = blockIdx.y, nb = blockIdx.x * 64;
  const int wv = threadIdx.x >> 6, lane = threadIdx.x & 63;
  const int li = lane & 15, g = lane >> 4;

  bf16x8 wf[2][4];
  float bo[2][4];
  #pragma unroll
  for (int tt = 0; tt < 2; ++tt) {
    const int ot = 2 * wv + tt;
    #pragma unroll
    for (int k = 0; k < 4; ++k)
      wf[tt][k] = *reinterpret_cast<const bf16x8*>(
          &Wb[(size_t)(ot * 16 + li) * CDIM + k * 32 + 8 * g]);
    #pragma unroll
    for (int r = 0; r < 4; ++r) bo[tt][r] = bout[ot * 16 + 4 * g + r];
  }
  #pragma unroll
  for (int nt = 0; nt < 4; ++nt) {
    bf16x8 bfr[4];
    #pragma unroll
    for (int k = 0; k < 4; ++k)
      bfr[k] = *reinterpret_cast<const bf16x8*>(
          &att[(((size_t)(b * 4 + k)) * NQ + nb + nt * 16 + li) * 32 + 8 * g]);
    #pragma unroll
    for (int tt = 0; tt < 2; ++tt) {
      f32x4 a; a[0] = a[1] = a[2] = a[3] = 0.f;
      #pragma unroll
      for (int k = 0; k < 4; ++k)
        a = __builtin_amdgcn_mfma_f32_16x16x32_bf16(wf[tt][k], bfr[k], a, 0, 0, 0);
      const int ot = 2 * wv + tt;
      #pragma unroll
      for (int r = 0; r < 4; ++r)
        out[((size_t)b * CDIM + ot * 16 + 4 * g + r) * NQ + nb + nt * 16 + li] =
            a[r] + bo[tt][r];
    }
  }
}

extern "C" void kernel_launch(void* const* d_in, const int* in_sizes, int n_in,
                              void* d_out, int out_size, void* d_ws, size_t ws_size,
                              hipStream_t stream) {
  const float* x    = (const float*)d_in[0];
  const float* memp = (const float*)d_in[1];
  const float* wqkv = (const float*)d_in[2];
  const float* wout = (const float*)d_in[3];
  const float* bout = (const float*)d_in[4];
  float* out = (float*)d_out;

  char* ws = (char*)d_ws;
  const size_t SZ  = (size_t)16 * NP * 32 * 2;              // Qt/Kt/Vt each
  const size_t ASZ = (size_t)16 * NQ * 32 * 2;              // att (bh,q,d) bf16
  __hip_bfloat16* Qt  = (__hip_bfloat16*)(ws);
  __hip_bfloat16* Kt  = (__hip_bfloat16*)(ws + SZ);
  __hip_bfloat16* Vt  = (__hip_bfloat16*)(ws + 2 * SZ);
  __hip_bfloat16* att = (__hip_bfloat16*)(ws + 3 * SZ);
  __hip_bfloat16* Wb  = (__hip_bfloat16*)(ws + 3 * SZ + ASZ);

  hipLaunchKernelGGL(k1_qkv, dim3(65, 4), dim3(256), 0, stream,
                     x, memp, wqkv, wout, Qt, Kt, Vt, Wb);
  hipLaunchKernelGGL(k2_attn, dim3(512), dim3(256), 0, stream, Qt, Kt, Vt, att);
  hipLaunchKernelGGL(k3_proj, dim3(64, 4), dim3(256), 0, stream, att, Wb, bout, out);
}